// Round 17
// baseline (331.347 us; speedup 1.0000x reference)
//
#include <hip/hip_runtime.h>
#include <hip/hip_bf16.h>
#include <math.h>

typedef short short8_t __attribute__((ext_vector_type(8)));
typedef float floatx4  __attribute__((ext_vector_type(4)));
typedef float floatx2  __attribute__((ext_vector_type(2)));
typedef unsigned int uint;

#define EPB 1024   // edges per histogram/scatter block
#define BSH 9      // 512 nodes per coarse bucket

// ---------------- bf16 helpers (RNE) ----------------------------------------

__device__ inline unsigned short f2b(float f) {
    uint u = __float_as_uint(f);
    u += 0x7fff + ((u >> 16) & 1);
    return (unsigned short)(u >> 16);
}
__device__ inline uint pack2(float a, float b) {
    return (uint)f2b(a) | ((uint)f2b(b) << 16);
}
__device__ inline float blo(uint v) { return __uint_as_float(v << 16); }
__device__ inline float bhi(uint v) { return __uint_as_float(v & 0xffff0000u); }

// ---------------- fp8 (e4m3) helpers ------------------------------------------

__device__ inline uint enc4_fp8(float f0, float f1, float f2, float f3) {
    uint v = __builtin_amdgcn_cvt_pk_fp8_f32(f0, f1, 0, false);
    v = __builtin_amdgcn_cvt_pk_fp8_f32(f2, f3, v, true);
    return v;
}
__device__ inline unsigned char enc1_fp8(float f) {
    return (unsigned char)(__builtin_amdgcn_cvt_pk_fp8_f32(f, f, 0, false) & 0xff);
}

// ---------------- CSR via bucketed counting sort ------------------------------
// Lesson ledger:
//  R10/R13: GLOBAL atomic histogram pinned ~43-50us (ILP/replication-invariant)
//       — replaced by LDS bucket histogram + counting sort (R16: -30us).
//  R12: co-scheduling light branches (<=1KB LDS, low VGPR) in one grid is free.
//  R11/R14: never mix an MFMA branch into a latency-bound grid.
//  R9: keep scatter targets packed/L2-resident (strided buckets -> 16x amp).
//  R16: harness ws re-poison (fillBuffer, 256MiB = ~40us @ 82% HBM) is fixed
//       overhead in every measurement — not addressable from kernel code.

__global__ __launch_bounds__(256) void k_phase_a(
    const int* __restrict__ dst, int* __restrict__ bhist, int E,
    const float* __restrict__ x, unsigned short* __restrict__ xb,
    unsigned char* __restrict__ xf8, int nX,
    const float* __restrict__ Wl1, const float* __restrict__ Wr1,
    const float* __restrict__ Wl2, const float* __restrict__ Wr2,
    unsigned short* __restrict__ wbuf,
    const int* __restrict__ batch, int* __restrict__ gstart, int N, int G,
    int bHist, int bCvtX, int bCvtW) {
    __shared__ int h[256];
    int b = blockIdx.x;
    int tid = threadIdx.x;
    if (b < bHist) {
        h[tid] = 0;
        __syncthreads();
        int e = b * EPB + tid * 4;
        if (e + 3 < E) {
            int4 d4 = *(const int4*)(dst + e);
            atomicAdd(&h[d4.x >> BSH], 1);
            atomicAdd(&h[d4.y >> BSH], 1);
            atomicAdd(&h[d4.z >> BSH], 1);
            atomicAdd(&h[d4.w >> BSH], 1);
        } else {
            for (int k = e; k < E; ++k) atomicAdd(&h[dst[k] >> BSH], 1);
        }
        __syncthreads();
        bhist[(size_t)b * 256 + tid] = h[tid];
    } else if (b < bHist + bCvtX) {
        int i = ((b - bHist) * 256 + tid) * 8;
        if (i < nX) {
            float4 v0 = *(const float4*)(x + i);
            float4 v1 = *(const float4*)(x + i + 4);
            uint4 ob;
            ob.x = pack2(v0.x, v0.y);
            ob.y = pack2(v0.z, v0.w);
            ob.z = pack2(v1.x, v1.y);
            ob.w = pack2(v1.z, v1.w);
            *(uint4*)(xb + i) = ob;
            uint2 of;
            of.x = enc4_fp8(v0.x, v0.y, v0.z, v0.w);
            of.y = enc4_fp8(v1.x, v1.y, v1.z, v1.w);
            *(uint2*)(xf8 + i) = of;
        }
    } else if (b < bHist + bCvtX + bCvtW) {
        int i = (b - bHist - bCvtX) * 256 + tid;
        if (i < 49152) {
            float v;
            if (i < 8192)       v = Wl1[i];
            else if (i < 16384) v = Wr1[i - 8192];
            else if (i < 32768) v = Wl2[i - 16384];
            else                v = Wr2[i - 32768];
            wbuf[i] = f2b(v);
        }
    } else {
        for (int g = tid; g <= G; g += 256) {
            if (g == G) { gstart[G] = N; continue; }
            int lo = 0, hi = N;
            while (lo < hi) {
                int mid = (lo + hi) >> 1;
                if (batch[mid] < g) lo = mid + 1; else hi = mid;
            }
            gstart[g] = lo;
        }
    }
}

__global__ __launch_bounds__(256) void k_scan_bh(int* __restrict__ bhist,
                                                 int* __restrict__ btot, int nb) {
    __shared__ int ss[256];
    int k = blockIdx.x;
    int t = threadIdx.x;
    int b0 = t * 4;
    int v[4];
    int sum = 0;
#pragma unroll
    for (int i = 0; i < 4; ++i) {
        int b = b0 + i;
        v[i] = (b < nb) ? bhist[(size_t)b * 256 + k] : 0;
        sum += v[i];
    }
    ss[t] = sum;
    __syncthreads();
#pragma unroll
    for (int off = 1; off < 256; off <<= 1) {
        int u = (t >= off) ? ss[t - off] : 0;
        __syncthreads();
        ss[t] += u;
        __syncthreads();
    }
    int run = ss[t] - sum;
#pragma unroll
    for (int i = 0; i < 4; ++i) {
        int b = b0 + i;
        if (b < nb) { bhist[(size_t)b * 256 + k] = run; run += v[i]; }
    }
    if (t == 0) btot[k] = ss[255];
}

__global__ void k_scan_btot(const int* __restrict__ btot, int* __restrict__ bbase,
                            int* __restrict__ row_start, int N, int E) {
    __shared__ int ss[256];
    int t = threadIdx.x;
    int v = btot[t];
    ss[t] = v;
    __syncthreads();
#pragma unroll
    for (int off = 1; off < 256; off <<= 1) {
        int u = (t >= off) ? ss[t - off] : 0;
        __syncthreads();
        ss[t] += u;
        __syncthreads();
    }
    bbase[t] = ss[t] - v;
    if (t == 255) bbase[256] = ss[255];
    if (t == 0) row_start[N] = E;
}

// record = (dst&511)<<23 | src   (requires src < 2^23)
__global__ __launch_bounds__(256) void k_scatter_b(
    const int* __restrict__ src, const int* __restrict__ dst,
    const int* __restrict__ bhist, const int* __restrict__ bbase,
    int* __restrict__ ebuf, int E) {
    __shared__ int lbase[256];
    int b = blockIdx.x;
    int t = threadIdx.x;
    lbase[t] = bbase[t] + bhist[(size_t)b * 256 + t];
    __syncthreads();
    int e = b * EPB + t * 4;
    if (e + 3 < E) {
        int4 d4 = *(const int4*)(dst + e);
        int4 s4 = *(const int4*)(src + e);
        int k, p;
        k = d4.x >> BSH; p = atomicAdd(&lbase[k], 1); ebuf[p] = ((d4.x & 511) << 23) | s4.x;
        k = d4.y >> BSH; p = atomicAdd(&lbase[k], 1); ebuf[p] = ((d4.y & 511) << 23) | s4.y;
        k = d4.z >> BSH; p = atomicAdd(&lbase[k], 1); ebuf[p] = ((d4.z & 511) << 23) | s4.z;
        k = d4.w >> BSH; p = atomicAdd(&lbase[k], 1); ebuf[p] = ((d4.w & 511) << 23) | s4.w;
    } else {
        for (int q = e; q < E; ++q) {
            int d = dst[q];
            int p = atomicAdd(&lbase[d >> BSH], 1);
            ebuf[p] = ((d & 511) << 23) | src[q];
        }
    }
}

__global__ __launch_bounds__(256) void k_bucket_csr(
    const int* __restrict__ ebuf, const int* __restrict__ bbase,
    int* __restrict__ row_start, int* __restrict__ csr_src, int N) {
    __shared__ int h2[512];
    __shared__ int ss[256];
    int k = blockIdx.x;
    int t = threadIdx.x;
    int node0 = k << BSH;
    int nn = N - node0; if (nn > 512) nn = 512;
    int s = bbase[k], e = bbase[k + 1];
    h2[t] = 0; h2[t + 256] = 0;
    __syncthreads();
    for (int i = s + t; i < e; i += 256)
        atomicAdd(&h2[((uint)ebuf[i]) >> 23], 1);
    __syncthreads();
    int a0 = h2[2 * t], a1 = h2[2 * t + 1];
    int ps = a0 + a1;
    ss[t] = ps;
    __syncthreads();
#pragma unroll
    for (int off = 1; off < 256; off <<= 1) {
        int u = (t >= off) ? ss[t - off] : 0;
        __syncthreads();
        ss[t] += u;
        __syncthreads();
    }
    int base = ss[t] - ps;
    h2[2 * t] = base;
    h2[2 * t + 1] = base + a0;
    __syncthreads();
    int rs0 = h2[t];
    int rs1 = h2[t + 256];
    __syncthreads();
    if (t < nn)       row_start[node0 + t]       = s + rs0;
    if (t + 256 < nn) row_start[node0 + t + 256] = s + rs1;
    for (int i = s + t; i < e; i += 256) {
        int rec = ebuf[i];
        int j = ((uint)rec) >> 23;
        int pos = atomicAdd(&h2[j], 1);
        csr_src[s + pos] = rec & 0x7FFFFF;
    }
}

// ---------------- mean aggregation (fp8 in, bf16 out, fp32 accumulate) -------
// R17: uint4 (16B) per lane — doubles rows-in-flight per wave vs uint2
// (gather2: 16, gather1: 32) and halves load-instruction count. The gathers
// are latency-serialization bound (R16: 55% stall-inflated VALUBusy).

#define ACCF8_16(v)                                                     \
    { floatx2 f = __builtin_amdgcn_cvt_pk_f32_fp8((v).x, false);        \
      a[0] += f[0]; a[1] += f[1];                                       \
      f = __builtin_amdgcn_cvt_pk_f32_fp8((v).x, true);                 \
      a[2] += f[0]; a[3] += f[1];                                       \
      f = __builtin_amdgcn_cvt_pk_f32_fp8((v).y, false);                \
      a[4] += f[0]; a[5] += f[1];                                       \
      f = __builtin_amdgcn_cvt_pk_f32_fp8((v).y, true);                 \
      a[6] += f[0]; a[7] += f[1];                                       \
      f = __builtin_amdgcn_cvt_pk_f32_fp8((v).z, false);                \
      a[8] += f[0]; a[9] += f[1];                                       \
      f = __builtin_amdgcn_cvt_pk_f32_fp8((v).z, true);                 \
      a[10] += f[0]; a[11] += f[1];                                     \
      f = __builtin_amdgcn_cvt_pk_f32_fp8((v).w, false);                \
      a[12] += f[0]; a[13] += f[1];                                     \
      f = __builtin_amdgcn_cvt_pk_f32_fp8((v).w, true);                 \
      a[14] += f[0]; a[15] += f[1]; }

// K=64: row = 64 B fp8 = 4 lanes x uint4. 16 edge-slots; 2-deep unroll.
__global__ void k_gather1(const unsigned char* __restrict__ xf8,
                          const int* __restrict__ row_start,
                          const int* __restrict__ csr_src,
                          unsigned short* __restrict__ agg, int n_nodes) {
    int tid = threadIdx.x;
    int node = blockIdx.x * 4 + (tid >> 6);
    if (node >= n_nodes) return;
    int lane = tid & 63;
    int grp = lane >> 2;       // edge slot 0..15
    int lp  = lane & 3;        // 4 lanes x 16B = 64 B row
    int s = row_start[node];
    int e = row_start[node + 1];
    float a[16];
#pragma unroll
    for (int q = 0; q < 16; ++q) a[q] = 0.f;
    int i = s + grp;
    for (; i + 16 < e; i += 32) {
        int u0 = csr_src[i];
        int u1 = csr_src[i + 16];
        uint4 v0 = *(const uint4*)(xf8 + (size_t)u0 * 64 + lp * 16);
        uint4 v1 = *(const uint4*)(xf8 + (size_t)u1 * 64 + lp * 16);
        ACCF8_16(v0);
        ACCF8_16(v1);
    }
    if (i < e) {
        int u0 = csr_src[i];
        uint4 v0 = *(const uint4*)(xf8 + (size_t)u0 * 64 + lp * 16);
        ACCF8_16(v0);
    }
#pragma unroll
    for (int q = 0; q < 16; ++q) {
        a[q] += __shfl_xor(a[q], 4);
        a[q] += __shfl_xor(a[q], 8);
        a[q] += __shfl_xor(a[q], 16);
        a[q] += __shfl_xor(a[q], 32);
    }
    if (grp == 0) {
        int d = e - s;
        float scale = (d > 0) ? (1.f / (float)d) : 1.f;
        uint4 o0, o1;
        o0.x = pack2(a[0] * scale,  a[1] * scale);
        o0.y = pack2(a[2] * scale,  a[3] * scale);
        o0.z = pack2(a[4] * scale,  a[5] * scale);
        o0.w = pack2(a[6] * scale,  a[7] * scale);
        o1.x = pack2(a[8] * scale,  a[9] * scale);
        o1.y = pack2(a[10] * scale, a[11] * scale);
        o1.z = pack2(a[12] * scale, a[13] * scale);
        o1.w = pack2(a[14] * scale, a[15] * scale);
        *(uint4*)(agg + (size_t)node * 64 + lp * 16)     = o0;
        *(uint4*)(agg + (size_t)node * 64 + lp * 16 + 8) = o1;
    }
}

// K=128: row = 128 B fp8 = 8 lanes x uint4. 8 edge-slots; 2-deep unroll.
__global__ void k_gather2(const unsigned char* __restrict__ h1f8,
                          const int* __restrict__ row_start,
                          const int* __restrict__ csr_src,
                          unsigned short* __restrict__ agg, int n_nodes) {
    int tid = threadIdx.x;
    int node = blockIdx.x * 4 + (tid >> 6);
    if (node >= n_nodes) return;
    int lane = tid & 63;
    int grp = lane >> 3;       // edge slot 0..7
    int lp  = lane & 7;        // 8 lanes x 16B = 128 B row
    int s = row_start[node];
    int e = row_start[node + 1];
    float a[16];
#pragma unroll
    for (int q = 0; q < 16; ++q) a[q] = 0.f;
    int i = s + grp;
    for (; i + 8 < e; i += 16) {
        int u0 = csr_src[i];
        int u1 = csr_src[i + 8];
        uint4 v0 = *(const uint4*)(h1f8 + (size_t)u0 * 128 + lp * 16);
        uint4 v1 = *(const uint4*)(h1f8 + (size_t)u1 * 128 + lp * 16);
        ACCF8_16(v0);
        ACCF8_16(v1);
    }
    if (i < e) {
        int u0 = csr_src[i];
        uint4 v0 = *(const uint4*)(h1f8 + (size_t)u0 * 128 + lp * 16);
        ACCF8_16(v0);
    }
#pragma unroll
    for (int q = 0; q < 16; ++q) {
        a[q] += __shfl_xor(a[q], 8);
        a[q] += __shfl_xor(a[q], 16);
        a[q] += __shfl_xor(a[q], 32);
    }
    if (grp == 0) {
        int d = e - s;
        float scale = (d > 0) ? (1.f / (float)d) : 1.f;
        uint4 o0, o1;
        o0.x = pack2(a[0] * scale,  a[1] * scale);
        o0.y = pack2(a[2] * scale,  a[3] * scale);
        o0.z = pack2(a[4] * scale,  a[5] * scale);
        o0.w = pack2(a[6] * scale,  a[7] * scale);
        o1.x = pack2(a[8] * scale,  a[9] * scale);
        o1.y = pack2(a[10] * scale, a[11] * scale);
        o1.z = pack2(a[12] * scale, a[13] * scale);
        o1.w = pack2(a[14] * scale, a[15] * scale);
        *(uint4*)(agg + (size_t)node * 128 + lp * 16)     = o0;
        *(uint4*)(agg + (size_t)node * 128 + lp * 16 + 8) = o1;
    }
}

// ---------------- MFMA SAGE linear: out = relu(agg@Wl.T + bl + xin@Wr.T) ----

template <int K, bool F8OUT>
__global__ __launch_bounds__(256) void k_linear_mfma(
    const unsigned short* __restrict__ aggA, const unsigned short* __restrict__ xinA,
    const unsigned short* __restrict__ Wlb,  const float* __restrict__ bl,
    const unsigned short* __restrict__ Wrb,  unsigned short* __restrict__ out,
    unsigned char* __restrict__ outf8, int n_nodes) {
    constexpr int NCH = (2 * K) / 32;
    __shared__ __align__(16) short As[128 * 32];   // 8 KB

    int tid  = threadIdx.x;
    int lane = tid & 63;
    int wave = tid >> 6;
    int quad = lane >> 4;
    int lr   = lane & 15;
    int node0 = blockIdx.x * 128;

    floatx4 acc[8][2];
#pragma unroll
    for (int mi = 0; mi < 8; ++mi)
#pragma unroll
        for (int ni = 0; ni < 2; ++ni)
            acc[mi][ni] = (floatx4){0.f, 0.f, 0.f, 0.f};

    int srow = tid >> 2;
    int sslot = tid & 3;

#pragma unroll
    for (int c = 0; c < NCH; ++c) {
        const unsigned short* srcA;
        const unsigned short* srcW;
        int kb;
        if (c < K / 32) { srcA = aggA; srcW = Wlb; kb = c * 32; }
        else            { srcA = xinA; srcW = Wrb; kb = c * 32 - K; }

        __syncthreads();
        {
            int n1 = node0 + srow;       if (n1 >= n_nodes) n1 = n_nodes - 1;
            int n2 = node0 + srow + 64;  if (n2 >= n_nodes) n2 = n_nodes - 1;
            uint4 v1 = *(const uint4*)(srcA + (size_t)n1 * K + kb + sslot * 8);
            uint4 v2 = *(const uint4*)(srcA + (size_t)n2 * K + kb + sslot * 8);
            *(uint4*)(&As[srow * 32 + sslot * 8]) = v1;
            *(uint4*)(&As[(srow + 64) * 32 + sslot * 8]) = v2;
        }
        __syncthreads();

        short8_t bfrag[2];
#pragma unroll
        for (int ni = 0; ni < 2; ++ni) {
            int j = wave * 32 + ni * 16 + lr;
            bfrag[ni] = *(const short8_t*)(srcW + (size_t)j * K + kb + quad * 8);
        }
#pragma unroll
        for (int mi = 0; mi < 8; ++mi) {
            short8_t af = *(const short8_t*)(&As[(mi * 16 + lr) * 32 + quad * 8]);
            acc[mi][0] = __builtin_amdgcn_mfma_f32_16x16x32_bf16(af, bfrag[0], acc[mi][0], 0, 0, 0);
            acc[mi][1] = __builtin_amdgcn_mfma_f32_16x16x32_bf16(af, bfrag[1], acc[mi][1], 0, 0, 0);
        }
    }

    float b0 = bl[wave * 32 + lr];
    float b1 = bl[wave * 32 + 16 + lr];
    int j0 = wave * 32 + lr;
#pragma unroll
    for (int mi = 0; mi < 8; ++mi) {
#pragma unroll
        for (int r = 0; r < 4; ++r) {
            int node = node0 + mi * 16 + quad * 4 + r;
            if (node < n_nodes) {
                float v0 = fmaxf(acc[mi][0][r] + b0, 0.f);
                float v1 = fmaxf(acc[mi][1][r] + b1, 0.f);
                out[(size_t)node * 128 + j0]      = f2b(v0);
                out[(size_t)node * 128 + j0 + 16] = f2b(v1);
                if (F8OUT) {
                    outf8[(size_t)node * 128 + j0]      = enc1_fp8(v0);
                    outf8[(size_t)node * 128 + j0 + 16] = enc1_fp8(v1);
                }
            }
        }
    }
}

// ---------------- fused pool + head -------------------------------------------

__global__ __launch_bounds__(256) void k_pool_head(const unsigned short* __restrict__ h2b,
                                                   const int* __restrict__ gstart,
                                                   const float* __restrict__ Wout,
                                                   const float* __restrict__ bout,
                                                   float* __restrict__ out) {
    int g = blockIdx.x;
    int s = gstart[g], e = gstart[g + 1];
    int lane = threadIdx.x & 63;
    int wave = threadIdx.x >> 6;
    float ax = 0.f, ay = 0.f;
    for (int n = s + wave; n < e; n += 4) {
        uint v = ((const uint*)(h2b + (size_t)n * 128))[lane];
        ax += blo(v);
        ay += bhi(v);
    }
    __shared__ float2 red[4][64];
    red[wave][lane] = make_float2(ax, ay);
    __syncthreads();
    if (wave == 0) {
        float2 a = red[0][lane], b = red[1][lane], c = red[2][lane], d = red[3][lane];
        float cnt = (float)(e - s);
        float inv = (cnt > 0.f) ? (1.f / cnt) : 1.f;
        float px = (a.x + b.x + c.x + d.x) * inv;
        float py = (a.y + b.y + c.y + d.y) * inv;
        float2 w0 = ((const float2*)(Wout))[lane];
        float2 w1 = ((const float2*)(Wout + 128))[lane];
        float d0 = px * w0.x + py * w0.y;
        float d1 = px * w1.x + py * w1.y;
#pragma unroll
        for (int m = 32; m > 0; m >>= 1) {
            d0 += __shfl_xor(d0, m);
            d1 += __shfl_xor(d1, m);
        }
        if (lane == 0) {
            float l0 = d0 + bout[0];
            float l1 = d1 + bout[1];
            float mx = fmaxf(l0, l1);
            float lse = mx + logf(expf(l0 - mx) + expf(l1 - mx));
            out[g * 2 + 0] = l0 - lse;
            out[g * 2 + 1] = l1 - lse;
        }
    }
}

// ---------------- launch -----------------------------------------------------

static inline size_t alignUp(size_t x, size_t a) { return (x + a - 1) & ~(a - 1); }

extern "C" void kernel_launch(void* const* d_in, const int* in_sizes, int n_in,
                              void* d_out, int out_size, void* d_ws, size_t ws_size,
                              hipStream_t stream) {
    const float* x    = (const float*)d_in[0];
    const int*   ei   = (const int*)d_in[1];
    const int*   batch= (const int*)d_in[2];
    const float* Wl1  = (const float*)d_in[3];
    const float* bl1  = (const float*)d_in[4];
    const float* Wr1  = (const float*)d_in[5];
    const float* Wl2  = (const float*)d_in[6];
    const float* bl2  = (const float*)d_in[7];
    const float* Wr2  = (const float*)d_in[8];
    const float* Wout = (const float*)d_in[9];
    const float* bout = (const float*)d_in[10];
    float* out = (float*)d_out;

    const int N = in_sizes[0] / 64;   // 100000 (must be < 2^23 for record packing)
    const int E = in_sizes[1] / 2;    // 1000000
    const int G = out_size / 2;       // 256

    const int* src = ei;
    const int* dst = ei + E;

    const int bHist = (E + EPB - 1) / EPB;     // 977
    const int NB    = (N + 511) >> BSH;        // 196 coarse buckets

    // workspace layout
    char* ws = (char*)d_ws;
    size_t off = 0;
    int*   bhist     = (int*)(ws + off); off = alignUp(off + (size_t)bHist * 256 * 4, 256);
    int*   btot      = (int*)(ws + off); off = alignUp(off + (size_t)257 * 4, 256);
    int*   bbase     = (int*)(ws + off); off = alignUp(off + (size_t)257 * 4, 256);
    int*   row_start = (int*)(ws + off); off = alignUp(off + (size_t)(N + 1) * 4, 256);
    int*   ebuf      = (int*)(ws + off); off = alignUp(off + (size_t)E * 4, 256);
    int*   csr_src   = (int*)(ws + off); off = alignUp(off + (size_t)E * 4, 256);
    int*   gstart    = (int*)(ws + off); off = alignUp(off + (size_t)(G + 1) * 4, 256);
    unsigned short* xb   = (unsigned short*)(ws + off); off = alignUp(off + (size_t)N * 64 * 2, 256);
    unsigned char*  xf8  = (unsigned char*)(ws + off);  off = alignUp(off + (size_t)N * 64, 256);
    unsigned short* wbuf = (unsigned short*)(ws + off); off = alignUp(off + (size_t)49152 * 2, 256);
    unsigned short* agg1 = (unsigned short*)(ws + off); off = alignUp(off + (size_t)N * 64 * 2, 256);
    unsigned short* h1   = (unsigned short*)(ws + off); off = alignUp(off + (size_t)N * 128 * 2, 256);
    unsigned char*  h1f8 = (unsigned char*)(ws + off);  off = alignUp(off + (size_t)N * 128, 256);
    unsigned short* agg2 = (unsigned short*)(ws + off); off = alignUp(off + (size_t)N * 128 * 2, 256);
    unsigned short* h2b  = (unsigned short*)(ws + off); off = alignUp(off + (size_t)N * 128 * 2, 256);
    (void)ws_size;

    unsigned short* Wl1b = wbuf;
    unsigned short* Wr1b = wbuf + 8192;
    unsigned short* Wl2b = wbuf + 16384;
    unsigned short* Wr2b = wbuf + 32768;

    // phase A: LDS bucket histogram + cvt_x + cvt_w + graph_bounds
    const int bCvtX = (N * 64 / 8 + 255) / 256;     // 3125
    const int bCvtW = 192;
    k_phase_a<<<bHist + bCvtX + bCvtW + 1, 256, 0, stream>>>(
        dst, bhist, E,
        x, xb, xf8, N * 64,
        Wl1, Wr1, Wl2, Wr2, wbuf,
        batch, gstart, N, G,
        bHist, bCvtX, bCvtW);

    // bucket scans + bucket-grouped scatter + per-bucket counting sort
    k_scan_bh<<<256, 256, 0, stream>>>(bhist, btot, bHist);
    k_scan_btot<<<1, 256, 0, stream>>>(btot, bbase, row_start, N, E);
    k_scatter_b<<<bHist, 256, 0, stream>>>(src, dst, bhist, bbase, ebuf, E);
    k_bucket_csr<<<NB, 256, 0, stream>>>(ebuf, bbase, row_start, csr_src, N);

    // layer 1: gather (fp8) -> MFMA linear (emits h1 bf16 + h1f8 fp8)
    k_gather1<<<(N + 3) / 4, 256, 0, stream>>>(xf8, row_start, csr_src, agg1, N);
    k_linear_mfma<64, true><<<(N + 127) / 128, 256, 0, stream>>>(
        agg1, xb, Wl1b, bl1, Wr1b, h1, h1f8, N);

    // layer 2
    k_gather2<<<(N + 3) / 4, 256, 0, stream>>>(h1f8, row_start, csr_src, agg2, N);
    k_linear_mfma<128, false><<<(N + 127) / 128, 256, 0, stream>>>(
        agg2, h1, Wl2b, bl2, Wr2b, h2b, (unsigned char*)nullptr, N);

    // fused pool + head
    k_pool_head<<<G, 256, 0, stream>>>(h2b, gstart, Wout, bout, out);
}

// Round 18
// 287.685 us; speedup vs baseline: 1.1518x; 1.1518x over previous
//
#include <hip/hip_runtime.h>
#include <hip/hip_bf16.h>
#include <math.h>

typedef short short8_t __attribute__((ext_vector_type(8)));
typedef float floatx4  __attribute__((ext_vector_type(4)));
typedef float floatx2  __attribute__((ext_vector_type(2)));
typedef unsigned int uint;

#define EPB 1024   // edges per histogram/scatter block
#define BSH 9      // 512 nodes per coarse bucket

// ---------------- bf16 helpers (RNE) ----------------------------------------

__device__ inline unsigned short f2b(float f) {
    uint u = __float_as_uint(f);
    u += 0x7fff + ((u >> 16) & 1);
    return (unsigned short)(u >> 16);
}
__device__ inline uint pack2(float a, float b) {
    return (uint)f2b(a) | ((uint)f2b(b) << 16);
}
__device__ inline float blo(uint v) { return __uint_as_float(v << 16); }
__device__ inline float bhi(uint v) { return __uint_as_float(v & 0xffff0000u); }

// ---------------- fp8 (e4m3) helpers ------------------------------------------

__device__ inline uint enc4_fp8(float f0, float f1, float f2, float f3) {
    uint v = __builtin_amdgcn_cvt_pk_fp8_f32(f0, f1, 0, false);
    v = __builtin_amdgcn_cvt_pk_fp8_f32(f2, f3, v, true);
    return v;
}
__device__ inline unsigned char enc1_fp8(float f) {
    return (unsigned char)(__builtin_amdgcn_cvt_pk_fp8_f32(f, f, 0, false) & 0xff);
}

// ---------------- CSR via bucketed counting sort ------------------------------
// Lesson ledger:
//  R10/R13: GLOBAL atomic histogram pinned ~43-50us (ILP/replication-invariant)
//       — replaced by LDS bucket histogram + counting sort (R16: -30us).
//  R12: co-scheduling light branches (<=1KB LDS, low VGPR) in one grid is free.
//  R11/R14: never mix an MFMA branch into a latency-bound grid.
//  R9: keep scatter targets packed/L2-resident (strided buckets -> 16x amp).
//  R16: harness ws re-poison (fillBuffer, 256MiB = ~40us @ 82% HBM) is fixed
//       overhead in every measurement — not addressable from kernel code.
//  R17: gather rows-in-flight is capped by degree (~10), not slot count;
//       wider lanes (uint4) + more slots only grew the shuffle-reduce tree
//       (64 shfl+add/node) — gather1 15->73us. R16 shapes are the optimum.

__global__ __launch_bounds__(256) void k_phase_a(
    const int* __restrict__ dst, int* __restrict__ bhist, int E,
    const float* __restrict__ x, unsigned short* __restrict__ xb,
    unsigned char* __restrict__ xf8, int nX,
    const float* __restrict__ Wl1, const float* __restrict__ Wr1,
    const float* __restrict__ Wl2, const float* __restrict__ Wr2,
    unsigned short* __restrict__ wbuf,
    const int* __restrict__ batch, int* __restrict__ gstart, int N, int G,
    int bHist, int bCvtX, int bCvtW) {
    __shared__ int h[256];
    int b = blockIdx.x;
    int tid = threadIdx.x;
    if (b < bHist) {
        h[tid] = 0;
        __syncthreads();
        int e = b * EPB + tid * 4;
        if (e + 3 < E) {
            int4 d4 = *(const int4*)(dst + e);
            atomicAdd(&h[d4.x >> BSH], 1);
            atomicAdd(&h[d4.y >> BSH], 1);
            atomicAdd(&h[d4.z >> BSH], 1);
            atomicAdd(&h[d4.w >> BSH], 1);
        } else {
            for (int k = e; k < E; ++k) atomicAdd(&h[dst[k] >> BSH], 1);
        }
        __syncthreads();
        bhist[(size_t)b * 256 + tid] = h[tid];
    } else if (b < bHist + bCvtX) {
        int i = ((b - bHist) * 256 + tid) * 8;
        if (i < nX) {
            float4 v0 = *(const float4*)(x + i);
            float4 v1 = *(const float4*)(x + i + 4);
            uint4 ob;
            ob.x = pack2(v0.x, v0.y);
            ob.y = pack2(v0.z, v0.w);
            ob.z = pack2(v1.x, v1.y);
            ob.w = pack2(v1.z, v1.w);
            *(uint4*)(xb + i) = ob;
            uint2 of;
            of.x = enc4_fp8(v0.x, v0.y, v0.z, v0.w);
            of.y = enc4_fp8(v1.x, v1.y, v1.z, v1.w);
            *(uint2*)(xf8 + i) = of;
        }
    } else if (b < bHist + bCvtX + bCvtW) {
        int i = (b - bHist - bCvtX) * 256 + tid;
        if (i < 49152) {
            float v;
            if (i < 8192)       v = Wl1[i];
            else if (i < 16384) v = Wr1[i - 8192];
            else if (i < 32768) v = Wl2[i - 16384];
            else                v = Wr2[i - 32768];
            wbuf[i] = f2b(v);
        }
    } else {
        for (int g = tid; g <= G; g += 256) {
            if (g == G) { gstart[G] = N; continue; }
            int lo = 0, hi = N;
            while (lo < hi) {
                int mid = (lo + hi) >> 1;
                if (batch[mid] < g) lo = mid + 1; else hi = mid;
            }
            gstart[g] = lo;
        }
    }
}

__global__ __launch_bounds__(256) void k_scan_bh(int* __restrict__ bhist,
                                                 int* __restrict__ btot, int nb) {
    __shared__ int ss[256];
    int k = blockIdx.x;
    int t = threadIdx.x;
    int b0 = t * 4;
    int v[4];
    int sum = 0;
#pragma unroll
    for (int i = 0; i < 4; ++i) {
        int b = b0 + i;
        v[i] = (b < nb) ? bhist[(size_t)b * 256 + k] : 0;
        sum += v[i];
    }
    ss[t] = sum;
    __syncthreads();
#pragma unroll
    for (int off = 1; off < 256; off <<= 1) {
        int u = (t >= off) ? ss[t - off] : 0;
        __syncthreads();
        ss[t] += u;
        __syncthreads();
    }
    int run = ss[t] - sum;
#pragma unroll
    for (int i = 0; i < 4; ++i) {
        int b = b0 + i;
        if (b < nb) { bhist[(size_t)b * 256 + k] = run; run += v[i]; }
    }
    if (t == 0) btot[k] = ss[255];
}

__global__ void k_scan_btot(const int* __restrict__ btot, int* __restrict__ bbase,
                            int* __restrict__ row_start, int N, int E) {
    __shared__ int ss[256];
    int t = threadIdx.x;
    int v = btot[t];
    ss[t] = v;
    __syncthreads();
#pragma unroll
    for (int off = 1; off < 256; off <<= 1) {
        int u = (t >= off) ? ss[t - off] : 0;
        __syncthreads();
        ss[t] += u;
        __syncthreads();
    }
    bbase[t] = ss[t] - v;
    if (t == 255) bbase[256] = ss[255];
    if (t == 0) row_start[N] = E;
}

// record = (dst&511)<<23 | src   (requires src < 2^23)
__global__ __launch_bounds__(256) void k_scatter_b(
    const int* __restrict__ src, const int* __restrict__ dst,
    const int* __restrict__ bhist, const int* __restrict__ bbase,
    int* __restrict__ ebuf, int E) {
    __shared__ int lbase[256];
    int b = blockIdx.x;
    int t = threadIdx.x;
    lbase[t] = bbase[t] + bhist[(size_t)b * 256 + t];
    __syncthreads();
    int e = b * EPB + t * 4;
    if (e + 3 < E) {
        int4 d4 = *(const int4*)(dst + e);
        int4 s4 = *(const int4*)(src + e);
        int k, p;
        k = d4.x >> BSH; p = atomicAdd(&lbase[k], 1); ebuf[p] = ((d4.x & 511) << 23) | s4.x;
        k = d4.y >> BSH; p = atomicAdd(&lbase[k], 1); ebuf[p] = ((d4.y & 511) << 23) | s4.y;
        k = d4.z >> BSH; p = atomicAdd(&lbase[k], 1); ebuf[p] = ((d4.z & 511) << 23) | s4.z;
        k = d4.w >> BSH; p = atomicAdd(&lbase[k], 1); ebuf[p] = ((d4.w & 511) << 23) | s4.w;
    } else {
        for (int q = e; q < E; ++q) {
            int d = dst[q];
            int p = atomicAdd(&lbase[d >> BSH], 1);
            ebuf[p] = ((d & 511) << 23) | src[q];
        }
    }
}

__global__ __launch_bounds__(256) void k_bucket_csr(
    const int* __restrict__ ebuf, const int* __restrict__ bbase,
    int* __restrict__ row_start, int* __restrict__ csr_src, int N) {
    __shared__ int h2[512];
    __shared__ int ss[256];
    int k = blockIdx.x;
    int t = threadIdx.x;
    int node0 = k << BSH;
    int nn = N - node0; if (nn > 512) nn = 512;
    int s = bbase[k], e = bbase[k + 1];
    h2[t] = 0; h2[t + 256] = 0;
    __syncthreads();
    for (int i = s + t; i < e; i += 256)
        atomicAdd(&h2[((uint)ebuf[i]) >> 23], 1);
    __syncthreads();
    int a0 = h2[2 * t], a1 = h2[2 * t + 1];
    int ps = a0 + a1;
    ss[t] = ps;
    __syncthreads();
#pragma unroll
    for (int off = 1; off < 256; off <<= 1) {
        int u = (t >= off) ? ss[t - off] : 0;
        __syncthreads();
        ss[t] += u;
        __syncthreads();
    }
    int base = ss[t] - ps;
    h2[2 * t] = base;
    h2[2 * t + 1] = base + a0;
    __syncthreads();
    int rs0 = h2[t];
    int rs1 = h2[t + 256];
    __syncthreads();
    if (t < nn)       row_start[node0 + t]       = s + rs0;
    if (t + 256 < nn) row_start[node0 + t + 256] = s + rs1;
    for (int i = s + t; i < e; i += 256) {
        int rec = ebuf[i];
        int j = ((uint)rec) >> 23;
        int pos = atomicAdd(&h2[j], 1);
        csr_src[s + pos] = rec & 0x7FFFFF;
    }
}

// ---------------- mean aggregation (fp8 in, bf16 out, fp32 accumulate) -------

#define ACCF8(v)                                                        \
    { floatx2 f = __builtin_amdgcn_cvt_pk_f32_fp8((v).x, false);        \
      a[0] += f[0]; a[1] += f[1];                                       \
      f = __builtin_amdgcn_cvt_pk_f32_fp8((v).x, true);                 \
      a[2] += f[0]; a[3] += f[1];                                       \
      f = __builtin_amdgcn_cvt_pk_f32_fp8((v).y, false);                \
      a[4] += f[0]; a[5] += f[1];                                       \
      f = __builtin_amdgcn_cvt_pk_f32_fp8((v).y, true);                 \
      a[6] += f[0]; a[7] += f[1]; }

// K=64: row = 64 B fp8. 8 edge-slots x 8 lanes x uint2; 2-deep unroll.
__global__ void k_gather1(const unsigned char* __restrict__ xf8,
                          const int* __restrict__ row_start,
                          const int* __restrict__ csr_src,
                          unsigned short* __restrict__ agg, int n_nodes) {
    int tid = threadIdx.x;
    int node = blockIdx.x * 4 + (tid >> 6);
    if (node >= n_nodes) return;
    int lane = tid & 63;
    int grp = lane >> 3;
    int lp  = lane & 7;
    int s = row_start[node];
    int e = row_start[node + 1];
    float a[8];
#pragma unroll
    for (int q = 0; q < 8; ++q) a[q] = 0.f;
    int i = s + grp;
    for (; i + 8 < e; i += 16) {
        int u0 = csr_src[i];
        int u1 = csr_src[i + 8];
        uint2 v0 = *(const uint2*)(xf8 + (size_t)u0 * 64 + lp * 8);
        uint2 v1 = *(const uint2*)(xf8 + (size_t)u1 * 64 + lp * 8);
        ACCF8(v0);
        ACCF8(v1);
    }
    if (i < e) {
        int u0 = csr_src[i];
        uint2 v0 = *(const uint2*)(xf8 + (size_t)u0 * 64 + lp * 8);
        ACCF8(v0);
    }
#pragma unroll
    for (int q = 0; q < 8; ++q) {
        a[q] += __shfl_xor(a[q], 8);
        a[q] += __shfl_xor(a[q], 16);
        a[q] += __shfl_xor(a[q], 32);
    }
    if (grp == 0) {
        int d = e - s;
        float scale = (d > 0) ? (1.f / (float)d) : 1.f;
        uint4 o;
        o.x = pack2(a[0] * scale, a[1] * scale);
        o.y = pack2(a[2] * scale, a[3] * scale);
        o.z = pack2(a[4] * scale, a[5] * scale);
        o.w = pack2(a[6] * scale, a[7] * scale);
        *(uint4*)(agg + (size_t)node * 64 + lp * 8) = o;
    }
}

// K=128: row = 128 B fp8. 4 edge-slots x 16 lanes x uint2; 2-deep unroll.
__global__ void k_gather2(const unsigned char* __restrict__ h1f8,
                          const int* __restrict__ row_start,
                          const int* __restrict__ csr_src,
                          unsigned short* __restrict__ agg, int n_nodes) {
    int tid = threadIdx.x;
    int node = blockIdx.x * 4 + (tid >> 6);
    if (node >= n_nodes) return;
    int lane = tid & 63;
    int grp = lane >> 4;
    int lp  = lane & 15;
    int s = row_start[node];
    int e = row_start[node + 1];
    float a[8];
#pragma unroll
    for (int q = 0; q < 8; ++q) a[q] = 0.f;
    int i = s + grp;
    for (; i + 4 < e; i += 8) {
        int u0 = csr_src[i];
        int u1 = csr_src[i + 4];
        uint2 v0 = *(const uint2*)(h1f8 + (size_t)u0 * 128 + lp * 8);
        uint2 v1 = *(const uint2*)(h1f8 + (size_t)u1 * 128 + lp * 8);
        ACCF8(v0);
        ACCF8(v1);
    }
    if (i < e) {
        int u0 = csr_src[i];
        uint2 v0 = *(const uint2*)(h1f8 + (size_t)u0 * 128 + lp * 8);
        ACCF8(v0);
    }
#pragma unroll
    for (int q = 0; q < 8; ++q) {
        a[q] += __shfl_xor(a[q], 16);
        a[q] += __shfl_xor(a[q], 32);
    }
    if (grp == 0) {
        int d = e - s;
        float scale = (d > 0) ? (1.f / (float)d) : 1.f;
        uint4 o;
        o.x = pack2(a[0] * scale, a[1] * scale);
        o.y = pack2(a[2] * scale, a[3] * scale);
        o.z = pack2(a[4] * scale, a[5] * scale);
        o.w = pack2(a[6] * scale, a[7] * scale);
        *(uint4*)(agg + (size_t)node * 128 + lp * 8) = o;
    }
}

// ---------------- MFMA SAGE linear: out = relu(agg@Wl.T + bl + xin@Wr.T) ----

template <int K, bool F8OUT>
__global__ __launch_bounds__(256) void k_linear_mfma(
    const unsigned short* __restrict__ aggA, const unsigned short* __restrict__ xinA,
    const unsigned short* __restrict__ Wlb,  const float* __restrict__ bl,
    const unsigned short* __restrict__ Wrb,  unsigned short* __restrict__ out,
    unsigned char* __restrict__ outf8, int n_nodes) {
    constexpr int NCH = (2 * K) / 32;
    __shared__ __align__(16) short As[128 * 32];   // 8 KB

    int tid  = threadIdx.x;
    int lane = tid & 63;
    int wave = tid >> 6;
    int quad = lane >> 4;
    int lr   = lane & 15;
    int node0 = blockIdx.x * 128;

    floatx4 acc[8][2];
#pragma unroll
    for (int mi = 0; mi < 8; ++mi)
#pragma unroll
        for (int ni = 0; ni < 2; ++ni)
            acc[mi][ni] = (floatx4){0.f, 0.f, 0.f, 0.f};

    int srow = tid >> 2;
    int sslot = tid & 3;

#pragma unroll
    for (int c = 0; c < NCH; ++c) {
        const unsigned short* srcA;
        const unsigned short* srcW;
        int kb;
        if (c < K / 32) { srcA = aggA; srcW = Wlb; kb = c * 32; }
        else            { srcA = xinA; srcW = Wrb; kb = c * 32 - K; }

        __syncthreads();
        {
            int n1 = node0 + srow;       if (n1 >= n_nodes) n1 = n_nodes - 1;
            int n2 = node0 + srow + 64;  if (n2 >= n_nodes) n2 = n_nodes - 1;
            uint4 v1 = *(const uint4*)(srcA + (size_t)n1 * K + kb + sslot * 8);
            uint4 v2 = *(const uint4*)(srcA + (size_t)n2 * K + kb + sslot * 8);
            *(uint4*)(&As[srow * 32 + sslot * 8]) = v1;
            *(uint4*)(&As[(srow + 64) * 32 + sslot * 8]) = v2;
        }
        __syncthreads();

        short8_t bfrag[2];
#pragma unroll
        for (int ni = 0; ni < 2; ++ni) {
            int j = wave * 32 + ni * 16 + lr;
            bfrag[ni] = *(const short8_t*)(srcW + (size_t)j * K + kb + quad * 8);
        }
#pragma unroll
        for (int mi = 0; mi < 8; ++mi) {
            short8_t af = *(const short8_t*)(&As[(mi * 16 + lr) * 32 + quad * 8]);
            acc[mi][0] = __builtin_amdgcn_mfma_f32_16x16x32_bf16(af, bfrag[0], acc[mi][0], 0, 0, 0);
            acc[mi][1] = __builtin_amdgcn_mfma_f32_16x16x32_bf16(af, bfrag[1], acc[mi][1], 0, 0, 0);
        }
    }

    float b0 = bl[wave * 32 + lr];
    float b1 = bl[wave * 32 + 16 + lr];
    int j0 = wave * 32 + lr;
#pragma unroll
    for (int mi = 0; mi < 8; ++mi) {
#pragma unroll
        for (int r = 0; r < 4; ++r) {
            int node = node0 + mi * 16 + quad * 4 + r;
            if (node < n_nodes) {
                float v0 = fmaxf(acc[mi][0][r] + b0, 0.f);
                float v1 = fmaxf(acc[mi][1][r] + b1, 0.f);
                out[(size_t)node * 128 + j0]      = f2b(v0);
                out[(size_t)node * 128 + j0 + 16] = f2b(v1);
                if (F8OUT) {
                    outf8[(size_t)node * 128 + j0]      = enc1_fp8(v0);
                    outf8[(size_t)node * 128 + j0 + 16] = enc1_fp8(v1);
                }
            }
        }
    }
}

// ---------------- fused pool + head -------------------------------------------

__global__ __launch_bounds__(256) void k_pool_head(const unsigned short* __restrict__ h2b,
                                                   const int* __restrict__ gstart,
                                                   const float* __restrict__ Wout,
                                                   const float* __restrict__ bout,
                                                   float* __restrict__ out) {
    int g = blockIdx.x;
    int s = gstart[g], e = gstart[g + 1];
    int lane = threadIdx.x & 63;
    int wave = threadIdx.x >> 6;
    float ax = 0.f, ay = 0.f;
    for (int n = s + wave; n < e; n += 4) {
        uint v = ((const uint*)(h2b + (size_t)n * 128))[lane];
        ax += blo(v);
        ay += bhi(v);
    }
    __shared__ float2 red[4][64];
    red[wave][lane] = make_float2(ax, ay);
    __syncthreads();
    if (wave == 0) {
        float2 a = red[0][lane], b = red[1][lane], c = red[2][lane], d = red[3][lane];
        float cnt = (float)(e - s);
        float inv = (cnt > 0.f) ? (1.f / cnt) : 1.f;
        float px = (a.x + b.x + c.x + d.x) * inv;
        float py = (a.y + b.y + c.y + d.y) * inv;
        float2 w0 = ((const float2*)(Wout))[lane];
        float2 w1 = ((const float2*)(Wout + 128))[lane];
        float d0 = px * w0.x + py * w0.y;
        float d1 = px * w1.x + py * w1.y;
#pragma unroll
        for (int m = 32; m > 0; m >>= 1) {
            d0 += __shfl_xor(d0, m);
            d1 += __shfl_xor(d1, m);
        }
        if (lane == 0) {
            float l0 = d0 + bout[0];
            float l1 = d1 + bout[1];
            float mx = fmaxf(l0, l1);
            float lse = mx + logf(expf(l0 - mx) + expf(l1 - mx));
            out[g * 2 + 0] = l0 - lse;
            out[g * 2 + 1] = l1 - lse;
        }
    }
}

// ---------------- launch -----------------------------------------------------

static inline size_t alignUp(size_t x, size_t a) { return (x + a - 1) & ~(a - 1); }

extern "C" void kernel_launch(void* const* d_in, const int* in_sizes, int n_in,
                              void* d_out, int out_size, void* d_ws, size_t ws_size,
                              hipStream_t stream) {
    const float* x    = (const float*)d_in[0];
    const int*   ei   = (const int*)d_in[1];
    const int*   batch= (const int*)d_in[2];
    const float* Wl1  = (const float*)d_in[3];
    const float* bl1  = (const float*)d_in[4];
    const float* Wr1  = (const float*)d_in[5];
    const float* Wl2  = (const float*)d_in[6];
    const float* bl2  = (const float*)d_in[7];
    const float* Wr2  = (const float*)d_in[8];
    const float* Wout = (const float*)d_in[9];
    const float* bout = (const float*)d_in[10];
    float* out = (float*)d_out;

    const int N = in_sizes[0] / 64;   // 100000 (must be < 2^23 for record packing)
    const int E = in_sizes[1] / 2;    // 1000000
    const int G = out_size / 2;       // 256

    const int* src = ei;
    const int* dst = ei + E;

    const int bHist = (E + EPB - 1) / EPB;     // 977
    const int NB    = (N + 511) >> BSH;        // 196 coarse buckets

    // workspace layout
    char* ws = (char*)d_ws;
    size_t off = 0;
    int*   bhist     = (int*)(ws + off); off = alignUp(off + (size_t)bHist * 256 * 4, 256);
    int*   btot      = (int*)(ws + off); off = alignUp(off + (size_t)257 * 4, 256);
    int*   bbase     = (int*)(ws + off); off = alignUp(off + (size_t)257 * 4, 256);
    int*   row_start = (int*)(ws + off); off = alignUp(off + (size_t)(N + 1) * 4, 256);
    int*   ebuf      = (int*)(ws + off); off = alignUp(off + (size_t)E * 4, 256);
    int*   csr_src   = (int*)(ws + off); off = alignUp(off + (size_t)E * 4, 256);
    int*   gstart    = (int*)(ws + off); off = alignUp(off + (size_t)(G + 1) * 4, 256);
    unsigned short* xb   = (unsigned short*)(ws + off); off = alignUp(off + (size_t)N * 64 * 2, 256);
    unsigned char*  xf8  = (unsigned char*)(ws + off);  off = alignUp(off + (size_t)N * 64, 256);
    unsigned short* wbuf = (unsigned short*)(ws + off); off = alignUp(off + (size_t)49152 * 2, 256);
    unsigned short* agg1 = (unsigned short*)(ws + off); off = alignUp(off + (size_t)N * 64 * 2, 256);
    unsigned short* h1   = (unsigned short*)(ws + off); off = alignUp(off + (size_t)N * 128 * 2, 256);
    unsigned char*  h1f8 = (unsigned char*)(ws + off);  off = alignUp(off + (size_t)N * 128, 256);
    unsigned short* agg2 = (unsigned short*)(ws + off); off = alignUp(off + (size_t)N * 128 * 2, 256);
    unsigned short* h2b  = (unsigned short*)(ws + off); off = alignUp(off + (size_t)N * 128 * 2, 256);
    (void)ws_size;

    unsigned short* Wl1b = wbuf;
    unsigned short* Wr1b = wbuf + 8192;
    unsigned short* Wl2b = wbuf + 16384;
    unsigned short* Wr2b = wbuf + 32768;

    // phase A: LDS bucket histogram + cvt_x + cvt_w + graph_bounds
    const int bCvtX = (N * 64 / 8 + 255) / 256;     // 3125
    const int bCvtW = 192;
    k_phase_a<<<bHist + bCvtX + bCvtW + 1, 256, 0, stream>>>(
        dst, bhist, E,
        x, xb, xf8, N * 64,
        Wl1, Wr1, Wl2, Wr2, wbuf,
        batch, gstart, N, G,
        bHist, bCvtX, bCvtW);

    // bucket scans + bucket-grouped scatter + per-bucket counting sort
    k_scan_bh<<<256, 256, 0, stream>>>(bhist, btot, bHist);
    k_scan_btot<<<1, 256, 0, stream>>>(btot, bbase, row_start, N, E);
    k_scatter_b<<<bHist, 256, 0, stream>>>(src, dst, bhist, bbase, ebuf, E);
    k_bucket_csr<<<NB, 256, 0, stream>>>(ebuf, bbase, row_start, csr_src, N);

    // layer 1: gather (fp8) -> MFMA linear (emits h1 bf16 + h1f8 fp8)
    k_gather1<<<(N + 3) / 4, 256, 0, stream>>>(xf8, row_start, csr_src, agg1, N);
    k_linear_mfma<64, true><<<(N + 127) / 128, 256, 0, stream>>>(
        agg1, xb, Wl1b, bl1, Wr1b, h1, h1f8, N);

    // layer 2
    k_gather2<<<(N + 3) / 4, 256, 0, stream>>>(h1f8, row_start, csr_src, agg2, N);
    k_linear_mfma<128, false><<<(N + 127) / 128, 256, 0, stream>>>(
        agg2, h1, Wl2b, bl2, Wr2b, h2b, (unsigned char*)nullptr, N);

    // fused pool + head
    k_pool_head<<<G, 256, 0, stream>>>(h2b, gstart, Wout, bout, out);
}